// Round 18
// baseline (516.512 us; speedup 1.0000x reference)
//
#include <hip/hip_runtime.h>

#define N_NODES 100000
#define HID 256
#define N_EDGES 1500000
#define N_REL 3
#define E_PER_REL (N_EDGES / N_REL)
#define NKEYS (N_REL * N_NODES)
#define KP 640                 // proj K  (256 + 384)
#define KR 768                 // relation K (3 * 256)

#define SCAN_CHUNK 1024
#define NSCANBLK ((NKEYS + SCAN_CHUNK - 1) / SCAN_CHUNK)   // 293

typedef __attribute__((ext_vector_type(8))) short bf16x8;
typedef __attribute__((ext_vector_type(4))) float f32x4;
typedef __attribute__((ext_vector_type(4))) int   i32x4;

__device__ __forceinline__ short f2bf(float x) {  // RNE f32 -> bf16
    union { float f; unsigned u; } v; v.f = x;
    unsigned r = v.u + 0x7fffu + ((v.u >> 16) & 1u);
    return (short)(r >> 16);
}
// 4-slot swizzle (64B rows of 4 x 16B): phys = slot ^ xorf(row)
__device__ __forceinline__ int xorf(int r) { return (r & 3) ^ ((r >> 2) & 3); }

// async global->LDS, 16B/lane; LDS dest = wave-uniform base + lane*16
__device__ __forceinline__ void gload16(const void* g, void* l) {
    typedef const __attribute__((address_space(1))) unsigned int gq;
    typedef __attribute__((address_space(3))) unsigned int lq;
    __builtin_amdgcn_global_load_lds((gq*)g, (lq*)l, 16, 0, 0);
}

// ---------------------------------------------------------------------------
// Weight prep 1: WTp[c][k] = bf16(0.5 * Wp[k][c])  (Wp = [Wa;Wb])
// ---------------------------------------------------------------------------
__global__ __launch_bounds__(256) void wprep_kernel(
    const float* __restrict__ Wa, const float* __restrict__ Wb,
    short* __restrict__ WTp)
{
    int idx = blockIdx.x * 256 + threadIdx.x;
    if (idx < 256 * KP) {
        int c = idx / KP, k = idx - c * KP;
        float v = (k < 256) ? Wa[k * HID + c] : Wb[(k - 256) * HID + c];
        WTp[idx] = f2bf(0.5f * v);
    }
}

// ---------------------------------------------------------------------------
// Weight prep 2: per-output-col int8 quantization of Wr.
// Block c: WTrq[c][k] = int8(Wr[k>>8][k&255][c] / sB[c]),
// sB[c] = colmax/127.  256 blocks x 256 threads (3 k-values per thread).
// ---------------------------------------------------------------------------
__global__ __launch_bounds__(256) void wprep2_kernel(
    const float* __restrict__ Wr,
    signed char* __restrict__ WTrq, float* __restrict__ sB)
{
    __shared__ float red[4];
    const int c = blockIdx.x;
    const int tid = threadIdx.x;
    const int lane = tid & 63;
    float v[3];
    float mx = 0.f;
    #pragma unroll
    for (int j = 0; j < 3; ++j) {
        int k = tid * 3 + j;
        v[j] = Wr[(k >> 8) * (HID * HID) + (k & 255) * HID + c];
        mx = fmaxf(mx, fabsf(v[j]));
    }
    #pragma unroll
    for (int off = 1; off < 64; off <<= 1)
        mx = fmaxf(mx, __shfl_xor(mx, off, 64));
    if (lane == 0) red[tid >> 6] = mx;
    __syncthreads();
    mx = fmaxf(fmaxf(red[0], red[1]), fmaxf(red[2], red[3]));
    if (tid == 0) sB[c] = mx * (1.0f / 127.0f);
    float qinv = (mx > 0.f) ? 127.0f / mx : 0.f;
    #pragma unroll
    for (int j = 0; j < 3; ++j)
        WTrq[(size_t)c * KR + tid * 3 + j] = (signed char)(int)rintf(v[j] * qinv);
}

// ---------------------------------------------------------------------------
// proj GEMM, tile 256x256 (unchanged r17): h0q[N,256] int8 + h0scale[N].
// 3-buffer ring (144 KB), pure-DMA staging, counted vmcnt 12/6/0.
// ---------------------------------------------------------------------------
__global__ __launch_bounds__(512, 2) void proj_gemm(
    const float* __restrict__ fa, const float* __restrict__ fb,
    const short* __restrict__ WTp,
    unsigned char* __restrict__ h0q, float* __restrict__ h0scale)
{
    __shared__ alignas(16) char lds[147456];   // 3 x (A 32K f32 + B 16K bf16)
    const int tid = threadIdx.x;
    const int lane = tid & 63;
    const int w = tid >> 6;
    const int wr = w >> 1, wc = w & 1;
    const int brow = blockIdx.x * 256;

    auto bufA = [&](int b) -> char* { return lds + b * 49152; };
    auto bufB = [&](int b) -> char* { return lds + b * 49152 + 32768; };

    f32x4 acc[4][8] = {};

    const int a_r8 = lane >> 3;
    const int a_sl = (lane & 7) ^ a_r8;
    int aRowG[4];
    #pragma unroll
    for (int ii = 0; ii < 4; ++ii) {
        int i = w * 4 + ii;
        int gr = brow + i * 8 + a_r8;
        aRowG[ii] = (gr < N_NODES) ? gr : (N_NODES - 1);
    }
    const int b_c16 = lane >> 2;
    int bColL[2], bSl[2];
    #pragma unroll
    for (int ii = 0; ii < 2; ++ii) {
        int i = w * 2 + ii;
        bColL[ii] = i * 16 + b_c16;
        bSl[ii] = (lane & 3) ^ xorf(bColL[ii]);
    }

    auto stage = [&](int b, int k0) {   // 6 loads/wave
        const float* asrc; int astr, kk;
        if (k0 < 256) { asrc = fa; astr = 256; kk = k0; }
        else          { asrc = fb; astr = 384; kk = k0 - 256; }
        #pragma unroll
        for (int ii = 0; ii < 4; ++ii) {
            int i = w * 4 + ii;
            gload16(asrc + (size_t)aRowG[ii] * astr + kk + a_sl * 4,
                    bufA(b) + i * 1024);
        }
        #pragma unroll
        for (int ii = 0; ii < 2; ++ii) {
            int i = w * 2 + ii;
            gload16(WTp + (size_t)bColL[ii] * KP + k0 + bSl[ii] * 8,
                    bufB(b) + i * 1024);
        }
    };

    const int nt = KP / 32;   // 20
    stage(0, 0); stage(1, 32); stage(2, 64);
    int cur = 0;
    for (int t = 0; t < nt; ++t) {
        if (t < nt - 2)       asm volatile("s_waitcnt vmcnt(12)" ::: "memory");
        else if (t == nt - 2) asm volatile("s_waitcnt vmcnt(6)" ::: "memory");
        else                  asm volatile("s_waitcnt vmcnt(0)" ::: "memory");
        __builtin_amdgcn_s_barrier();

        bf16x8 afr[4], bfr[8];
        #pragma unroll
        for (int m = 0; m < 4; ++m) {
            int rt = wr * 64 + m * 16 + (lane & 15);
            int p0 = (((lane >> 4) << 1) | 0) ^ (rt & 7);
            int p1 = (((lane >> 4) << 1) | 1) ^ (rt & 7);
            f32x4 lo = *(const f32x4*)(bufA(cur) + rt * 128 + p0 * 16);
            f32x4 hi = *(const f32x4*)(bufA(cur) + rt * 128 + p1 * 16);
            union { bf16x8 h; unsigned u[4]; } cv;
            asm("v_cvt_pk_bf16_f32 %0, %1, %2" : "=v"(cv.u[0]) : "v"(lo.x), "v"(lo.y));
            asm("v_cvt_pk_bf16_f32 %0, %1, %2" : "=v"(cv.u[1]) : "v"(lo.z), "v"(lo.w));
            asm("v_cvt_pk_bf16_f32 %0, %1, %2" : "=v"(cv.u[2]) : "v"(hi.x), "v"(hi.y));
            asm("v_cvt_pk_bf16_f32 %0, %1, %2" : "=v"(cv.u[3]) : "v"(hi.z), "v"(hi.w));
            afr[m] = cv.h;
        }
        #pragma unroll
        for (int n = 0; n < 8; ++n) {
            int ct = wc * 128 + n * 16 + (lane & 15);
            int p = (lane >> 4) ^ xorf(ct);
            bfr[n] = *(const bf16x8*)(bufB(cur) + ct * 64 + p * 16);
        }
        #pragma unroll
        for (int m = 0; m < 4; ++m)
            #pragma unroll
            for (int n = 0; n < 8; ++n)
                acc[m][n] = __builtin_amdgcn_mfma_f32_16x16x32_bf16(
                    afr[m], bfr[n], acc[m][n], 0, 0, 0);

        asm volatile("s_waitcnt lgkmcnt(0)" ::: "memory");
        __builtin_amdgcn_sched_barrier(0);
        __builtin_amdgcn_s_barrier();
        if (t + 3 < nt) stage(cur, (t + 3) * 32);
        cur = (cur == 2) ? 0 : cur + 1;
    }

    // ---- per-row absmax -> int8 scale (overlay dead ring LDS) ----
    float* redM  = (float*)lds;          // [256][2]
    float* smInv = redM + 512;           // [256]
    #pragma unroll
    for (int m = 0; m < 4; ++m) {
        #pragma unroll
        for (int j = 0; j < 4; ++j) {
            int lrow = wr * 64 + m * 16 + ((lane >> 4) << 2) + j;
            float mx = 0.f;
            #pragma unroll
            for (int n = 0; n < 8; ++n) mx = fmaxf(mx, fabsf(acc[m][n][j]));
            #pragma unroll
            for (int off = 1; off < 16; off <<= 1)
                mx = fmaxf(mx, __shfl_xor(mx, off, 64));
            if ((lane & 15) == 0) redM[lrow * 2 + wc] = mx;
        }
    }
    __syncthreads();
    if (tid < 256) {
        float rm = fmaxf(redM[tid * 2 + 0], redM[tid * 2 + 1]);
        int grow = brow + tid;
        smInv[tid] = (rm > 0.f) ? 127.0f / rm : 0.f;
        if (grow < N_NODES)
            h0scale[grow] = (grow == 0) ? 0.f : rm * (1.0f / 127.0f);
    }
    __syncthreads();

    #pragma unroll
    for (int m = 0; m < 4; ++m) {
        #pragma unroll
        for (int j = 0; j < 4; ++j) {
            int lrow = wr * 64 + m * 16 + ((lane >> 4) << 2) + j;
            int row = brow + lrow;
            if (row >= N_NODES) continue;
            float inv = smInv[lrow];
            #pragma unroll
            for (int n = 0; n < 8; ++n) {
                int col = wc * 128 + n * 16 + (lane & 15);
                int qi = (row == 0) ? 0 : (int)rintf(acc[m][n][j] * inv);
                h0q[(size_t)row * HID + col] = (unsigned char)(signed char)qi;
            }
        }
    }
}

// ---------------------------------------------------------------------------
// rel GEMM (int8 x int8 -> i32) + fused residual LayerNorm:
//   out = LN( dq(h0q) + dq(Sq @ WTrq^T) ) * gamma + beta, row 0 zeroed.
// Same 3-ring/byte-layout/vmcnt as r17 (rows stay 64B), but K-steps 24 -> 12
// (BK = 64 int8). i32 accum; per-256-k-segment fold with sS(row,seg); sB(col)
// applied in epilogue.
// ---------------------------------------------------------------------------
__global__ __launch_bounds__(512, 4) void rel_gemm_ln(
    const unsigned char* __restrict__ Sq, const signed char* __restrict__ WTrq,
    const float* __restrict__ sSg, const float* __restrict__ sB,
    const unsigned char* __restrict__ h0q, const float* __restrict__ h0scale,
    const float* __restrict__ gamma, const float* __restrict__ beta,
    float* __restrict__ out)
{
    __shared__ alignas(16) char lds[73728];   // 3 x (A 8K + B 16K)
    __shared__ float sS_lds[384];             // 128 rows x 3 segment scales
    const int tid = threadIdx.x;
    const int lane = tid & 63;
    const int w = tid >> 6;
    const int wr = w >> 2, wc = w & 3;
    const int brow = blockIdx.x * 128;

    auto bufA = [&](int b) -> char* { return lds + b * 24576; };
    auto bufB = [&](int b) -> char* { return lds + b * 24576 + 8192; };

    if (tid < 128) {
        int gr = brow + tid;
        if (gr >= N_NODES) gr = N_NODES - 1;
        #pragma unroll
        for (int j = 0; j < 3; ++j) sS_lds[tid * 3 + j] = sSg[gr * 3 + j];
    }

    i32x4 acci[4][4] = {};
    f32x4 accf[4][4] = {};

    const int s_r16 = lane >> 2;
    const int sRowL = w * 16 + s_r16;
    int gr0 = brow + sRowL;
    const int sRowG = (gr0 < N_NODES) ? gr0 : (N_NODES - 1);
    const int sSl = (lane & 3) ^ xorf(sRowL);
    const int b_c16 = lane >> 2;
    int bColL[2], bSl[2];
    #pragma unroll
    for (int ii = 0; ii < 2; ++ii) {
        int i = w * 2 + ii;
        bColL[ii] = i * 16 + b_c16;
        bSl[ii] = (lane & 3) ^ xorf(bColL[ii]);
    }

    auto stage = [&](int b, int k0) {   // 3 loads/wave (k0 in int8 elements)
        gload16(Sq + (size_t)sRowG * KR + k0 + sSl * 16, bufA(b) + w * 1024);
        #pragma unroll
        for (int ii = 0; ii < 2; ++ii) {
            int i = w * 2 + ii;
            gload16(WTrq + (size_t)bColL[ii] * KR + k0 + bSl[ii] * 16,
                    bufB(b) + i * 1024);
        }
    };

    const int nt = KR / 64;   // 12
    stage(0, 0); stage(1, 64); stage(2, 128);
    int cur = 0;
    for (int t = 0; t < nt; ++t) {
        if (t < nt - 2)       asm volatile("s_waitcnt vmcnt(6)" ::: "memory");
        else if (t == nt - 2) asm volatile("s_waitcnt vmcnt(3)" ::: "memory");
        else                  asm volatile("s_waitcnt vmcnt(0)" ::: "memory");
        __builtin_amdgcn_s_barrier();

        i32x4 afr[4], bfr[4];
        #pragma unroll
        for (int m = 0; m < 4; ++m) {
            int rt = wr * 64 + m * 16 + (lane & 15);
            int p = (lane >> 4) ^ xorf(rt);
            afr[m] = *(const i32x4*)(bufA(cur) + rt * 64 + p * 16);
        }
        #pragma unroll
        for (int n = 0; n < 4; ++n) {
            int ct = wc * 64 + n * 16 + (lane & 15);
            int p = (lane >> 4) ^ xorf(ct);
            bfr[n] = *(const i32x4*)(bufB(cur) + ct * 64 + p * 16);
        }
        #pragma unroll
        for (int m = 0; m < 4; ++m)
            #pragma unroll
            for (int n = 0; n < 4; ++n)
                acci[m][n] = __builtin_amdgcn_mfma_i32_16x16x64_i8(
                    afr[m], bfr[n], acci[m][n], 0, 0, 0);

        // segment boundary (k multiple of 256): fold i32 -> f32 with sS
        if ((t & 3) == 3) {
            int seg = t >> 2;
            #pragma unroll
            for (int m = 0; m < 4; ++m)
                #pragma unroll
                for (int j = 0; j < 4; ++j) {
                    int lrow = wr * 64 + m * 16 + ((lane >> 4) << 2) + j;
                    float sc = sS_lds[lrow * 3 + seg];
                    #pragma unroll
                    for (int n = 0; n < 4; ++n) {
                        accf[m][n][j] = fmaf(sc, (float)acci[m][n][j], accf[m][n][j]);
                        acci[m][n][j] = 0;
                    }
                }
        }

        asm volatile("s_waitcnt lgkmcnt(0)" ::: "memory");
        __builtin_amdgcn_sched_barrier(0);
        __builtin_amdgcn_s_barrier();
        if (t + 3 < nt) stage(cur, (t + 3) * 64);
        cur = (cur == 2) ? 0 : cur + 1;
    }

    // ---- epilogue: x = accf*sB + dq(h0q) ; per-row mean/var ; LN ; write ----
    float* redS  = (float*)lds;          // [128][4]
    float* redS2 = redS + 512;           // [128][4]
    float* smMean = redS2 + 512;         // [128]
    float* smRs   = smMean + 128;        // [128]

    float gk[4], bk[4], sbv[4];
    #pragma unroll
    for (int n = 0; n < 4; ++n) {
        int col = wc * 64 + n * 16 + (lane & 15);
        gk[n] = gamma[col];
        bk[n] = beta[col];
        sbv[n] = sB[col];
    }

    __syncthreads();   // ring LDS dead; safe to overlay
    #pragma unroll
    for (int m = 0; m < 4; ++m) {
        #pragma unroll
        for (int j = 0; j < 4; ++j) {
            int lrow = wr * 64 + m * 16 + ((lane >> 4) << 2) + j;
            int grow = brow + lrow;
            int crow = (grow < N_NODES) ? grow : 0;
            float sc = h0scale[crow];
            float s = 0.f, s2 = 0.f;
            #pragma unroll
            for (int n = 0; n < 4; ++n) {
                int col = wc * 64 + n * 16 + (lane & 15);
                float hq = (float)(int)(signed char)h0q[(size_t)crow * HID + col];
                float x = accf[m][n][j] * sbv[n] + hq * sc;
                accf[m][n][j] = x;
                s += x; s2 = fmaf(x, x, s2);
            }
            #pragma unroll
            for (int off = 1; off < 16; off <<= 1) {
                s += __shfl_xor(s, off, 64);
                s2 += __shfl_xor(s2, off, 64);
            }
            if ((lane & 15) == 0) { redS[lrow * 4 + wc] = s; redS2[lrow * 4 + wc] = s2; }
        }
    }
    __syncthreads();
    if (tid < 128) {
        float tot  = redS[tid * 4 + 0] + redS[tid * 4 + 1] + redS[tid * 4 + 2] + redS[tid * 4 + 3];
        float tot2 = redS2[tid * 4 + 0] + redS2[tid * 4 + 1] + redS2[tid * 4 + 2] + redS2[tid * 4 + 3];
        float mean = tot * (1.0f / HID);
        float var = tot2 * (1.0f / HID) - mean * mean;
        smMean[tid] = mean;
        smRs[tid] = rsqrtf(var + 1e-5f);
    }
    __syncthreads();
    #pragma unroll
    for (int m = 0; m < 4; ++m) {
        #pragma unroll
        for (int j = 0; j < 4; ++j) {
            int lrow = wr * 64 + m * 16 + ((lane >> 4) << 2) + j;
            int grow = brow + lrow;
            if (grow >= N_NODES) continue;
            float mean = smMean[lrow], rs = smRs[lrow];
            #pragma unroll
            for (int n = 0; n < 4; ++n) {
                int col = wc * 64 + n * 16 + (lane & 15);
                float y = (accf[m][n][j] - mean) * rs * gk[n] + bk[n];
                out[(size_t)grow * HID + col] = (grow == 0) ? 0.f : y;
            }
        }
    }
}

// ---------------------------------------------------------------------------
// CSR build: histogram -> hierarchical exclusive scan -> bucket fill
// ---------------------------------------------------------------------------
__global__ __launch_bounds__(256) void hist_kernel(
    const int* __restrict__ dst, int* __restrict__ count)
{
    int i = blockIdx.x * 256 + threadIdx.x;
    if (i >= N_EDGES) return;
    int r = i / E_PER_REL;
    atomicAdd(&count[r * N_NODES + dst[i]], 1);
}

__global__ __launch_bounds__(256) void scan1_kernel(
    const int* __restrict__ count, int* __restrict__ offset,
    int* __restrict__ bsum)
{
    __shared__ int tmp[256];
    const int t = threadIdx.x;
    const int base = blockIdx.x * SCAN_CHUNK + t * 4;
    int v[4];
    #pragma unroll
    for (int j = 0; j < 4; ++j)
        v[j] = (base + j < NKEYS) ? count[base + j] : 0;
    int tsum = v[0] + v[1] + v[2] + v[3];
    tmp[t] = tsum;
    __syncthreads();
    #pragma unroll
    for (int off = 1; off < 256; off <<= 1) {
        int x = (t >= off) ? tmp[t - off] : 0;
        __syncthreads();
        tmp[t] += x;
        __syncthreads();
    }
    int run = tmp[t] - tsum;
    #pragma unroll
    for (int j = 0; j < 4; ++j) {
        if (base + j < NKEYS) offset[base + j] = run;
        run += v[j];
    }
    if (t == 0) bsum[blockIdx.x] = tmp[255];
}

__global__ __launch_bounds__(256) void scan2_kernel(int* __restrict__ bsum)
{
    __shared__ int tmp[256];
    const int t = threadIdx.x;
    int v0 = (2 * t     < NSCANBLK) ? bsum[2 * t]     : 0;
    int v1 = (2 * t + 1 < NSCANBLK) ? bsum[2 * t + 1] : 0;
    int psum = v0 + v1;
    tmp[t] = psum;
    __syncthreads();
    #pragma unroll
    for (int off = 1; off < 256; off <<= 1) {
        int x = (t >= off) ? tmp[t - off] : 0;
        __syncthreads();
        tmp[t] += x;
        __syncthreads();
    }
    int excl = tmp[t] - psum;
    if (2 * t     < NSCANBLK) bsum[2 * t]     = excl;
    if (2 * t + 1 < NSCANBLK) bsum[2 * t + 1] = excl + v0;
}

__global__ __launch_bounds__(256) void scan3_kernel(
    int* __restrict__ offset, const int* __restrict__ bsum)
{
    int i = blockIdx.x * 256 + threadIdx.x;
    if (i >= NKEYS) return;
    offset[i] += bsum[i / SCAN_CHUNK];
}

__global__ __launch_bounds__(256) void fill_kernel(
    const int* __restrict__ src, const int* __restrict__ dst,
    const float* __restrict__ w, const float* __restrict__ h0scale,
    int* __restrict__ offset, int4* __restrict__ csr4)
{
    int i = blockIdx.x * 256 + threadIdx.x;
    if (i >= N_EDGES) return;
    int r = i / E_PER_REL;
    int key = r * N_NODES + dst[i];
    int pos = atomicAdd(&offset[key], 1);
    int s = src[i];
    float wt = w[i];
    float ws = wt * h0scale[s];
    csr4[pos] = make_int4(s, __float_as_int(wt), __float_as_int(ws), 0);
}

// ---------------------------------------------------------------------------
// Gather (int8 rows in, int8 rows out): one wave per (relation, node).
// Output quantized per (node, r): Sq[node][r*256..] + sSg[node*3+r].
// ---------------------------------------------------------------------------
__global__ __launch_bounds__(256) void gather_kernel(
    const unsigned char* __restrict__ h0q,
    const int* __restrict__ ends, const int* __restrict__ count,
    const int4* __restrict__ csr4,
    unsigned char* __restrict__ Sq, float* __restrict__ sSg)
{
    int gw = (blockIdx.x * 256 + threadIdx.x) >> 6;
    int lane = threadIdx.x & 63;
    if (gw >= N_REL * N_NODES) return;
    int r = gw / N_NODES;
    int node = gw - r * N_NODES;
    int deg = count[gw];
    int end = ends[gw];
    int start = end - deg;
    const int colo = lane * 4;

    float a0 = 0.f, a1 = 0.f, a2 = 0.f, a3 = 0.f;
    float den = 0.f;

    if (deg > 0) {
        int degc = (deg < 64) ? deg : 64;
        int4 e = csr4[start + ((lane < degc) ? lane : 0)];
        int msrc = e.x;
        float mw = (lane < degc) ? __int_as_float(e.y) : 0.f;
        int mws = (lane < degc) ? e.z : 0;

        float d = mw;
        #pragma unroll
        for (int off = 1; off < 64; off <<= 1) d += __shfl_xor(d, off, 64);
        den = d;

        int p = 0;
        for (; p + 4 <= degc; p += 4) {
            #pragma unroll
            for (int j = 0; j < 4; ++j) {
                int q = p + j;
                int sj = __builtin_amdgcn_readlane(msrc, q);
                float wsj = __int_as_float(__builtin_amdgcn_readlane(mws, q));
                unsigned qv = *(const unsigned*)(h0q + (size_t)sj * HID + colo);
                a0 = fmaf(wsj, (float)(int)(signed char)(qv & 255u), a0);
                a1 = fmaf(wsj, (float)(int)(signed char)((qv >> 8) & 255u), a1);
                a2 = fmaf(wsj, (float)(int)(signed char)((qv >> 16) & 255u), a2);
                a3 = fmaf(wsj, (float)(int)(signed char)(qv >> 24), a3);
            }
        }
        for (; p < degc; ++p) {
            int sj = __builtin_amdgcn_readlane(msrc, p);
            float wsj = __int_as_float(__builtin_amdgcn_readlane(mws, p));
            unsigned qv = *(const unsigned*)(h0q + (size_t)sj * HID + colo);
            a0 = fmaf(wsj, (float)(int)(signed char)(qv & 255u), a0);
            a1 = fmaf(wsj, (float)(int)(signed char)((qv >> 8) & 255u), a1);
            a2 = fmaf(wsj, (float)(int)(signed char)((qv >> 16) & 255u), a2);
            a3 = fmaf(wsj, (float)(int)(signed char)(qv >> 24), a3);
        }
        for (int pp = start + 64; pp < end; ++pp) {
            int4 ee = csr4[pp];
            float wt = __int_as_float(ee.y);
            float wsj = __int_as_float(ee.z);
            unsigned qv = *(const unsigned*)(h0q + (size_t)ee.x * HID + colo);
            a0 = fmaf(wsj, (float)(int)(signed char)(qv & 255u), a0);
            a1 = fmaf(wsj, (float)(int)(signed char)((qv >> 8) & 255u), a1);
            a2 = fmaf(wsj, (float)(int)(signed char)((qv >> 16) & 255u), a2);
            a3 = fmaf(wsj, (float)(int)(signed char)(qv >> 24), a3);
            den += wt;
        }
    }

    float inv = 1.0f / fmaxf(den, 1e-8f);
    float av0 = a0 * inv, av1 = a1 * inv, av2 = a2 * inv, av3 = a3 * inv;

    // per-(node,r) int8 quantization
    float mx = fmaxf(fmaxf(fabsf(av0), fabsf(av1)), fmaxf(fabsf(av2), fabsf(av3)));
    #pragma unroll
    for (int off = 1; off < 64; off <<= 1)
        mx = fmaxf(mx, __shfl_xor(mx, off, 64));
    float qinv = (mx > 0.f) ? 127.0f / mx : 0.f;
    int q0 = (int)rintf(av0 * qinv);
    int q1 = (int)rintf(av1 * qinv);
    int q2 = (int)rintf(av2 * qinv);
    int q3 = (int)rintf(av3 * qinv);
    unsigned packed = (unsigned)(q0 & 255) | ((unsigned)(q1 & 255) << 8)
                    | ((unsigned)(q2 & 255) << 16) | ((unsigned)(q3 & 255) << 24);
    *(unsigned*)(Sq + (size_t)node * KR + r * HID + colo) = packed;
    if (lane == 0) sSg[node * 3 + r] = mx * (1.0f / 127.0f);
}

// ---------------------------------------------------------------------------
extern "C" void kernel_launch(void* const* d_in, const int* in_sizes, int n_in,
                              void* d_out, int out_size, void* d_ws, size_t ws_size,
                              hipStream_t stream) {
    const float* fa    = (const float*)d_in[0];
    const float* fb    = (const float*)d_in[1];
    const float* Wa    = (const float*)d_in[2];
    const float* Wb    = (const float*)d_in[3];
    const float* Wr    = (const float*)d_in[4];
    const float* gamma = (const float*)d_in[5];
    const float* beta  = (const float*)d_in[6];
    const float* ew    = (const float*)d_in[7];
    const int*   esrc  = (const int*)d_in[8];
    const int*   edst  = (const int*)d_in[9];
    float* out = (float*)d_out;

    char* ws = (char*)d_ws;
    size_t off = 0;
    unsigned char* Sq   = (unsigned char*)(ws + off); off += (size_t)N_NODES * KR;   // 76.8 MB
    short* WTp          = (short*)(ws + off);        off += (size_t)256 * KP * 2;
    signed char* WTrq   = (signed char*)(ws + off);  off += (size_t)256 * KR;
    float* sB           = (float*)(ws + off);        off += 256 * 4;
    int*   count        = (int*)(ws + off);          off += (size_t)NKEYS * 4;
    int*   offs         = (int*)(ws + off);          off += (size_t)NKEYS * 4;
    int*   bsum         = (int*)(ws + off);          off += 4096;
    int4*  csr4         = (int4*)(ws + off);         off += (size_t)N_EDGES * 16;    // 24 MB
    unsigned char* h0q  = (unsigned char*)(ws + off); off += (size_t)N_NODES * HID;  // 25.6 MB
    float* h0scale      = (float*)(ws + off);        off += (size_t)N_NODES * 4;
    float* sSg          = (float*)(ws + off);        off += (size_t)N_NODES * 3 * 4; // 1.2 MB

    wprep_kernel<<<(256 * KP) / 256, 256, 0, stream>>>(Wa, Wb, WTp);
    wprep2_kernel<<<256, 256, 0, stream>>>(Wr, WTrq, sB);

    const int ngridP = (N_NODES + 255) / 256;   // 391
    proj_gemm<<<ngridP, 512, 0, stream>>>(fa, fb, WTp, h0q, h0scale);

    // CSR build
    hipMemsetAsync(count, 0, (size_t)NKEYS * 4, stream);
    const int egrid = (N_EDGES + 255) / 256;
    hist_kernel<<<egrid, 256, 0, stream>>>(edst, count);
    scan1_kernel<<<NSCANBLK, 256, 0, stream>>>(count, offs, bsum);
    scan2_kernel<<<1, 256, 0, stream>>>(bsum);
    scan3_kernel<<<(NKEYS + 255) / 256, 256, 0, stream>>>(offs, bsum);
    fill_kernel<<<egrid, 256, 0, stream>>>(esrc, edst, ew, h0scale, offs, csr4);

    gather_kernel<<<(N_REL * N_NODES * 64) / 256, 256, 0, stream>>>(
        h0q, offs, count, csr4, Sq, sSg);

    const int ngridR = (N_NODES + 127) / 128;   // 782
    rel_gemm_ln<<<ngridR, 512, 0, stream>>>(
        Sq, WTrq, sSg, sB, h0q, h0scale, gamma, beta, out);
}

// Round 19
// 451.937 us; speedup vs baseline: 1.1429x; 1.1429x over previous
//
#include <hip/hip_runtime.h>

#define N_NODES 100000
#define HID 256
#define N_EDGES 1500000
#define N_REL 3
#define E_PER_REL (N_EDGES / N_REL)
#define NKEYS (N_REL * N_NODES)
#define KP 640                 // proj K  (256 + 384)
#define KR 768                 // relation K (3 * 256)

#define SCAN_CHUNK 1024
#define NSCANBLK ((NKEYS + SCAN_CHUNK - 1) / SCAN_CHUNK)   // 293

typedef __attribute__((ext_vector_type(8))) short bf16x8;
typedef __attribute__((ext_vector_type(4))) float f32x4;

__device__ __forceinline__ short f2bf(float x) {  // RNE f32 -> bf16
    union { float f; unsigned u; } v; v.f = x;
    unsigned r = v.u + 0x7fffu + ((v.u >> 16) & 1u);
    return (short)(r >> 16);
}
__device__ __forceinline__ float bf2f(short h) {
    union { unsigned u; float f; } v;
    v.u = ((unsigned)(unsigned short)h) << 16;
    return v.f;
}
// 4-slot swizzle (bf16 rows of 4 x 16B): phys = slot ^ xorf(row)
__device__ __forceinline__ int xorf(int r) { return (r & 3) ^ ((r >> 2) & 3); }

// async global->LDS, 16B/lane; LDS dest = wave-uniform base + lane*16
__device__ __forceinline__ void gload16(const void* g, void* l) {
    typedef const __attribute__((address_space(1))) unsigned int gq;
    typedef __attribute__((address_space(3))) unsigned int lq;
    __builtin_amdgcn_global_load_lds((gq*)g, (lq*)l, 16, 0, 0);
}

// ---------------------------------------------------------------------------
// Weight prep: WTp[c][k] = bf16(0.5 * Wp[k][c])  (Wp = [Wa;Wb], k in [0,640))
//              WTr[c][k] = bf16(Wr[k>>8][k&255][c])          (k in [0,768))
// ---------------------------------------------------------------------------
__global__ __launch_bounds__(256) void wprep_kernel(
    const float* __restrict__ Wa, const float* __restrict__ Wb,
    const float* __restrict__ Wr,
    short* __restrict__ WTp, short* __restrict__ WTr)
{
    int idx = blockIdx.x * 256 + threadIdx.x;
    if (idx < 256 * KP) {
        int c = idx / KP, k = idx - c * KP;
        float v = (k < 256) ? Wa[k * HID + c] : Wb[(k - 256) * HID + c];
        WTp[idx] = f2bf(0.5f * v);
    } else {
        int j = idx - 256 * KP;
        if (j < 256 * KR) {
            int c = j / KR, k = j - c * KR;
            WTr[j] = f2bf(Wr[(k >> 8) * HID * HID + (k & 255) * HID + c]);
        }
    }
}

// ---------------------------------------------------------------------------
// proj GEMM, tile 256x256: h0q[N,256] (int8) + h0scale[N] from
//   h0 = fa@(.5Wa) + fb@(.5Wb), row 0 zeroed.
// 8 waves (4 row x 2 col), wave tile 64x128, acc[4][8].
// 3-buffer ring (144 KB), pure-DMA staging, counted vmcnt 12/6/0.
// ---------------------------------------------------------------------------
__global__ __launch_bounds__(512, 2) void proj_gemm(
    const float* __restrict__ fa, const float* __restrict__ fb,
    const short* __restrict__ WTp,
    unsigned char* __restrict__ h0q, float* __restrict__ h0scale)
{
    __shared__ alignas(16) char lds[147456];   // 3 x (A 32K f32 + B 16K bf16)
    const int tid = threadIdx.x;
    const int lane = tid & 63;
    const int w = tid >> 6;
    const int wr = w >> 1, wc = w & 1;
    const int brow = blockIdx.x * 256;

    auto bufA = [&](int b) -> char* { return lds + b * 49152; };
    auto bufB = [&](int b) -> char* { return lds + b * 49152 + 32768; };

    f32x4 acc[4][8] = {};

    const int a_r8 = lane >> 3;
    const int a_sl = (lane & 7) ^ a_r8;
    int aRowG[4];
    #pragma unroll
    for (int ii = 0; ii < 4; ++ii) {
        int i = w * 4 + ii;
        int gr = brow + i * 8 + a_r8;
        aRowG[ii] = (gr < N_NODES) ? gr : (N_NODES - 1);
    }
    const int b_c16 = lane >> 2;
    int bColL[2], bSl[2];
    #pragma unroll
    for (int ii = 0; ii < 2; ++ii) {
        int i = w * 2 + ii;
        bColL[ii] = i * 16 + b_c16;
        bSl[ii] = (lane & 3) ^ xorf(bColL[ii]);
    }

    auto stage = [&](int b, int k0) {   // 6 loads/wave
        const float* asrc; int astr, kk;
        if (k0 < 256) { asrc = fa; astr = 256; kk = k0; }
        else          { asrc = fb; astr = 384; kk = k0 - 256; }
        #pragma unroll
        for (int ii = 0; ii < 4; ++ii) {
            int i = w * 4 + ii;
            gload16(asrc + (size_t)aRowG[ii] * astr + kk + a_sl * 4,
                    bufA(b) + i * 1024);
        }
        #pragma unroll
        for (int ii = 0; ii < 2; ++ii) {
            int i = w * 2 + ii;
            gload16(WTp + (size_t)bColL[ii] * KP + k0 + bSl[ii] * 8,
                    bufB(b) + i * 1024);
        }
    };

    const int nt = KP / 32;   // 20
    stage(0, 0); stage(1, 32); stage(2, 64);
    int cur = 0;
    for (int t = 0; t < nt; ++t) {
        if (t < nt - 2)       asm volatile("s_waitcnt vmcnt(12)" ::: "memory");
        else if (t == nt - 2) asm volatile("s_waitcnt vmcnt(6)" ::: "memory");
        else                  asm volatile("s_waitcnt vmcnt(0)" ::: "memory");
        __builtin_amdgcn_s_barrier();

        bf16x8 afr[4], bfr[8];
        #pragma unroll
        for (int m = 0; m < 4; ++m) {
            int rt = wr * 64 + m * 16 + (lane & 15);
            int p0 = (((lane >> 4) << 1) | 0) ^ (rt & 7);
            int p1 = (((lane >> 4) << 1) | 1) ^ (rt & 7);
            f32x4 lo = *(const f32x4*)(bufA(cur) + rt * 128 + p0 * 16);
            f32x4 hi = *(const f32x4*)(bufA(cur) + rt * 128 + p1 * 16);
            union { bf16x8 h; unsigned u[4]; } cv;
            asm("v_cvt_pk_bf16_f32 %0, %1, %2" : "=v"(cv.u[0]) : "v"(lo.x), "v"(lo.y));
            asm("v_cvt_pk_bf16_f32 %0, %1, %2" : "=v"(cv.u[1]) : "v"(lo.z), "v"(lo.w));
            asm("v_cvt_pk_bf16_f32 %0, %1, %2" : "=v"(cv.u[2]) : "v"(hi.x), "v"(hi.y));
            asm("v_cvt_pk_bf16_f32 %0, %1, %2" : "=v"(cv.u[3]) : "v"(hi.z), "v"(hi.w));
            afr[m] = cv.h;
        }
        #pragma unroll
        for (int n = 0; n < 8; ++n) {
            int ct = wc * 128 + n * 16 + (lane & 15);
            int p = (lane >> 4) ^ xorf(ct);
            bfr[n] = *(const bf16x8*)(bufB(cur) + ct * 64 + p * 16);
        }
        #pragma unroll
        for (int m = 0; m < 4; ++m)
            #pragma unroll
            for (int n = 0; n < 8; ++n)
                acc[m][n] = __builtin_amdgcn_mfma_f32_16x16x32_bf16(
                    afr[m], bfr[n], acc[m][n], 0, 0, 0);

        asm volatile("s_waitcnt lgkmcnt(0)" ::: "memory");
        __builtin_amdgcn_sched_barrier(0);
        __builtin_amdgcn_s_barrier();
        if (t + 3 < nt) stage(cur, (t + 3) * 32);
        cur = (cur == 2) ? 0 : cur + 1;
    }

    // ---- per-row absmax -> int8 scale (overlay dead ring LDS) ----
    float* redM  = (float*)lds;          // [256][2]
    float* smInv = redM + 512;           // [256]
    #pragma unroll
    for (int m = 0; m < 4; ++m) {
        #pragma unroll
        for (int j = 0; j < 4; ++j) {
            int lrow = wr * 64 + m * 16 + ((lane >> 4) << 2) + j;
            float mx = 0.f;
            #pragma unroll
            for (int n = 0; n < 8; ++n) mx = fmaxf(mx, fabsf(acc[m][n][j]));
            #pragma unroll
            for (int off = 1; off < 16; off <<= 1)
                mx = fmaxf(mx, __shfl_xor(mx, off, 64));
            if ((lane & 15) == 0) redM[lrow * 2 + wc] = mx;
        }
    }
    __syncthreads();
    if (tid < 256) {
        float rm = fmaxf(redM[tid * 2 + 0], redM[tid * 2 + 1]);
        int grow = brow + tid;
        smInv[tid] = (rm > 0.f) ? 127.0f / rm : 0.f;
        if (grow < N_NODES)
            h0scale[grow] = (grow == 0) ? 0.f : rm * (1.0f / 127.0f);
    }
    __syncthreads();

    #pragma unroll
    for (int m = 0; m < 4; ++m) {
        #pragma unroll
        for (int j = 0; j < 4; ++j) {
            int lrow = wr * 64 + m * 16 + ((lane >> 4) << 2) + j;
            int row = brow + lrow;
            if (row >= N_NODES) continue;
            float inv = smInv[lrow];
            #pragma unroll
            for (int n = 0; n < 8; ++n) {
                int col = wc * 128 + n * 16 + (lane & 15);
                int qi = (row == 0) ? 0 : (int)rintf(acc[m][n][j] * inv);
                h0q[(size_t)row * HID + col] = (unsigned char)(signed char)qi;
            }
        }
    }
}

// ---------------------------------------------------------------------------
// rel GEMM + fused residual LayerNorm (r17 bf16 3-ring structure):
//   out[N,256] (f32) = LN( dq(h0q) + S@WTr^T ) * gamma + beta, row 0 zeroed.
// ---------------------------------------------------------------------------
__global__ __launch_bounds__(512, 4) void rel_gemm_ln(
    const short* __restrict__ S, const short* __restrict__ WTr,
    const unsigned char* __restrict__ h0q, const float* __restrict__ h0scale,
    const float* __restrict__ gamma, const float* __restrict__ beta,
    float* __restrict__ out)
{
    __shared__ alignas(16) char lds[73728];   // 3 x (A 8K + B 16K)
    const int tid = threadIdx.x;
    const int lane = tid & 63;
    const int w = tid >> 6;
    const int wr = w >> 2, wc = w & 3;
    const int brow = blockIdx.x * 128;

    auto bufA = [&](int b) -> char* { return lds + b * 24576; };
    auto bufB = [&](int b) -> char* { return lds + b * 24576 + 8192; };

    f32x4 acc[4][4] = {};

    const int s_r16 = lane >> 2;
    const int sRowL = w * 16 + s_r16;
    int gr0 = brow + sRowL;
    const int sRowG = (gr0 < N_NODES) ? gr0 : (N_NODES - 1);
    const int sSl = (lane & 3) ^ xorf(sRowL);
    const int b_c16 = lane >> 2;
    int bColL[2], bSl[2];
    #pragma unroll
    for (int ii = 0; ii < 2; ++ii) {
        int i = w * 2 + ii;
        bColL[ii] = i * 16 + b_c16;
        bSl[ii] = (lane & 3) ^ xorf(bColL[ii]);
    }

    auto stage = [&](int b, int k0) {   // 3 loads/wave
        gload16(S + (size_t)sRowG * KR + k0 + sSl * 8, bufA(b) + w * 1024);
        #pragma unroll
        for (int ii = 0; ii < 2; ++ii) {
            int i = w * 2 + ii;
            gload16(WTr + (size_t)bColL[ii] * KR + k0 + bSl[ii] * 8,
                    bufB(b) + i * 1024);
        }
    };

    const int nt = KR / 32;   // 24
    stage(0, 0); stage(1, 32); stage(2, 64);
    int cur = 0;
    for (int t = 0; t < nt; ++t) {
        if (t < nt - 2)       asm volatile("s_waitcnt vmcnt(6)" ::: "memory");
        else if (t == nt - 2) asm volatile("s_waitcnt vmcnt(3)" ::: "memory");
        else                  asm volatile("s_waitcnt vmcnt(0)" ::: "memory");
        __builtin_amdgcn_s_barrier();

        bf16x8 afr[4], bfr[4];
        #pragma unroll
        for (int m = 0; m < 4; ++m) {
            int rt = wr * 64 + m * 16 + (lane & 15);
            int p = (lane >> 4) ^ xorf(rt);
            afr[m] = *(const bf16x8*)(bufA(cur) + rt * 64 + p * 16);
        }
        #pragma unroll
        for (int n = 0; n < 4; ++n) {
            int ct = wc * 64 + n * 16 + (lane & 15);
            int p = (lane >> 4) ^ xorf(ct);
            bfr[n] = *(const bf16x8*)(bufB(cur) + ct * 64 + p * 16);
        }
        #pragma unroll
        for (int m = 0; m < 4; ++m)
            #pragma unroll
            for (int n = 0; n < 4; ++n)
                acc[m][n] = __builtin_amdgcn_mfma_f32_16x16x32_bf16(
                    afr[m], bfr[n], acc[m][n], 0, 0, 0);

        asm volatile("s_waitcnt lgkmcnt(0)" ::: "memory");
        __builtin_amdgcn_sched_barrier(0);
        __builtin_amdgcn_s_barrier();
        if (t + 3 < nt) stage(cur, (t + 3) * 32);
        cur = (cur == 2) ? 0 : cur + 1;
    }

    // ---- epilogue: x = acc + dq(h0q) ; per-row mean/var ; LN ; write out ----
    float* redS  = (float*)lds;          // [128][4]
    float* redS2 = redS + 512;           // [128][4]
    float* smMean = redS2 + 512;         // [128]
    float* smRs   = smMean + 128;        // [128]

    float gk[4], bk[4];
    #pragma unroll
    for (int n = 0; n < 4; ++n) {
        int col = wc * 64 + n * 16 + (lane & 15);
        gk[n] = gamma[col];
        bk[n] = beta[col];
    }

    #pragma unroll
    for (int m = 0; m < 4; ++m) {
        #pragma unroll
        for (int j = 0; j < 4; ++j) {
            int lrow = wr * 64 + m * 16 + ((lane >> 4) << 2) + j;
            int grow = brow + lrow;
            int crow = (grow < N_NODES) ? grow : 0;
            float sc = h0scale[crow];
            float s = 0.f, s2 = 0.f;
            #pragma unroll
            for (int n = 0; n < 4; ++n) {
                int col = wc * 64 + n * 16 + (lane & 15);
                float hq = (float)(int)(signed char)h0q[(size_t)crow * HID + col];
                float x = acc[m][n][j] + hq * sc;
                acc[m][n][j] = x;
                s += x; s2 = fmaf(x, x, s2);
            }
            #pragma unroll
            for (int off = 1; off < 16; off <<= 1) {
                s += __shfl_xor(s, off, 64);
                s2 += __shfl_xor(s2, off, 64);
            }
            if ((lane & 15) == 0) { redS[lrow * 4 + wc] = s; redS2[lrow * 4 + wc] = s2; }
        }
    }
    __syncthreads();
    if (tid < 128) {
        float tot  = redS[tid * 4 + 0] + redS[tid * 4 + 1] + redS[tid * 4 + 2] + redS[tid * 4 + 3];
        float tot2 = redS2[tid * 4 + 0] + redS2[tid * 4 + 1] + redS2[tid * 4 + 2] + redS2[tid * 4 + 3];
        float mean = tot * (1.0f / HID);
        float var = tot2 * (1.0f / HID) - mean * mean;
        smMean[tid] = mean;
        smRs[tid] = rsqrtf(var + 1e-5f);
    }
    __syncthreads();
    #pragma unroll
    for (int m = 0; m < 4; ++m) {
        #pragma unroll
        for (int j = 0; j < 4; ++j) {
            int lrow = wr * 64 + m * 16 + ((lane >> 4) << 2) + j;
            int grow = brow + lrow;
            if (grow >= N_NODES) continue;
            float mean = smMean[lrow], rs = smRs[lrow];
            #pragma unroll
            for (int n = 0; n < 4; ++n) {
                int col = wc * 64 + n * 16 + (lane & 15);
                float y = (acc[m][n][j] - mean) * rs * gk[n] + bk[n];
                out[(size_t)grow * HID + col] = (grow == 0) ? 0.f : y;
            }
        }
    }
}

// ---------------------------------------------------------------------------
// CSR build: histogram -> 2-level scan (scan3 folded into fill/gather)
// csr4 = {src, w, w*scale[src], 0} -> dequant folded into edge weight.
// ---------------------------------------------------------------------------
__global__ __launch_bounds__(256) void hist_kernel(
    const int* __restrict__ dst, int* __restrict__ count)
{
    int i = blockIdx.x * 256 + threadIdx.x;
    if (i >= N_EDGES) return;
    int r = i / E_PER_REL;
    atomicAdd(&count[r * N_NODES + dst[i]], 1);
}

__global__ __launch_bounds__(256) void scan1_kernel(
    const int* __restrict__ count, int* __restrict__ offset,
    int* __restrict__ bsum)
{
    __shared__ int tmp[256];
    const int t = threadIdx.x;
    const int base = blockIdx.x * SCAN_CHUNK + t * 4;
    int v[4];
    #pragma unroll
    for (int j = 0; j < 4; ++j)
        v[j] = (base + j < NKEYS) ? count[base + j] : 0;
    int tsum = v[0] + v[1] + v[2] + v[3];
    tmp[t] = tsum;
    __syncthreads();
    #pragma unroll
    for (int off = 1; off < 256; off <<= 1) {
        int x = (t >= off) ? tmp[t - off] : 0;
        __syncthreads();
        tmp[t] += x;
        __syncthreads();
    }
    int run = tmp[t] - tsum;
    #pragma unroll
    for (int j = 0; j < 4; ++j) {
        if (base + j < NKEYS) offset[base + j] = run;
        run += v[j];
    }
    if (t == 0) bsum[blockIdx.x] = tmp[255];
}

__global__ __launch_bounds__(256) void scan2_kernel(int* __restrict__ bsum)
{
    __shared__ int tmp[256];
    const int t = threadIdx.x;
    int v0 = (2 * t     < NSCANBLK) ? bsum[2 * t]     : 0;
    int v1 = (2 * t + 1 < NSCANBLK) ? bsum[2 * t + 1] : 0;
    int psum = v0 + v1;
    tmp[t] = psum;
    __syncthreads();
    #pragma unroll
    for (int off = 1; off < 256; off <<= 1) {
        int x = (t >= off) ? tmp[t - off] : 0;
        __syncthreads();
        tmp[t] += x;
        __syncthreads();
    }
    int excl = tmp[t] - psum;
    if (2 * t     < NSCANBLK) bsum[2 * t]     = excl;
    if (2 * t + 1 < NSCANBLK) bsum[2 * t + 1] = excl + v0;
}

__global__ __launch_bounds__(256) void fill_kernel(
    const int* __restrict__ src, const int* __restrict__ dst,
    const float* __restrict__ w, const float* __restrict__ h0scale,
    int* __restrict__ offset, const int* __restrict__ bsum,
    int4* __restrict__ csr4)
{
    int i = blockIdx.x * 256 + threadIdx.x;
    if (i >= N_EDGES) return;
    int r = i / E_PER_REL;
    int key = r * N_NODES + dst[i];
    int pos = atomicAdd(&offset[key], 1) + bsum[key / SCAN_CHUNK];
    int s = src[i];
    float wt = w[i];
    float ws = wt * h0scale[s];
    csr4[pos] = make_int4(s, __float_as_int(wt), __float_as_int(ws), 0);
}

// ---------------------------------------------------------------------------
// Gather (int8 rows): one wave per (relation, node). Reads 256B h0q rows;
// decode = bfe+cvt. Dequant scale pre-folded into ws at fill time.
// den via wave reduction. Scalar-broadcast edges via readlane. S bf16.
// end = local_end + bsum[key/1024] (scan3 folded).
// ---------------------------------------------------------------------------
__global__ __launch_bounds__(256) void gather_kernel(
    const unsigned char* __restrict__ h0q,
    const int* __restrict__ ends, const int* __restrict__ count,
    const int* __restrict__ bsum,
    const int4* __restrict__ csr4,
    short* __restrict__ S)
{
    int gw = (blockIdx.x * 256 + threadIdx.x) >> 6;
    int lane = threadIdx.x & 63;
    if (gw >= N_REL * N_NODES) return;
    int r = gw / N_NODES;
    int node = gw - r * N_NODES;
    int deg = count[gw];
    int end = ends[gw] + bsum[gw / SCAN_CHUNK];
    int start = end - deg;
    const int colo = lane * 4;

    float a0 = 0.f, a1 = 0.f, a2 = 0.f, a3 = 0.f;
    float den = 0.f;

    if (deg > 0) {
        int degc = (deg < 64) ? deg : 64;
        int4 e = csr4[start + ((lane < degc) ? lane : 0)];
        int msrc = e.x;
        float mw = (lane < degc) ? __int_as_float(e.y) : 0.f;
        int mws = (lane < degc) ? e.z : 0;

        float d = mw;
        #pragma unroll
        for (int off = 1; off < 64; off <<= 1) d += __shfl_xor(d, off, 64);
        den = d;

        int p = 0;
        for (; p + 4 <= degc; p += 4) {
            #pragma unroll
            for (int j = 0; j < 4; ++j) {
                int q = p + j;
                int sj = __builtin_amdgcn_readlane(msrc, q);
                float wsj = __int_as_float(__builtin_amdgcn_readlane(mws, q));
                unsigned qv = *(const unsigned*)(h0q + (size_t)sj * HID + colo);
                a0 = fmaf(wsj, (float)(int)(signed char)(qv & 255u), a0);
                a1 = fmaf(wsj, (float)(int)(signed char)((qv >> 8) & 255u), a1);
                a2 = fmaf(wsj, (float)(int)(signed char)((qv >> 16) & 255u), a2);
                a3 = fmaf(wsj, (float)(int)(signed char)(qv >> 24), a3);
            }
        }
        for (; p < degc; ++p) {
            int sj = __builtin_amdgcn_readlane(msrc, p);
            float wsj = __int_as_float(__builtin_amdgcn_readlane(mws, p));
            unsigned qv = *(const unsigned*)(h0q + (size_t)sj * HID + colo);
            a0 = fmaf(wsj, (float)(int)(signed char)(qv & 255u), a0);
            a1 = fmaf(wsj, (float)(int)(signed char)((qv >> 8) & 255u), a1);
            a2 = fmaf(wsj, (float)(int)(signed char)((qv >> 16) & 255u), a2);
            a3 = fmaf(wsj, (float)(int)(signed char)(qv >> 24), a3);
        }
        for (int pp = start + 64; pp < end; ++pp) {
            int4 ee = csr4[pp];
            float wt = __int_as_float(ee.y);
            float wsj = __int_as_float(ee.z);
            unsigned qv = *(const unsigned*)(h0q + (size_t)ee.x * HID + colo);
            a0 = fmaf(wsj, (float)(int)(signed char)(qv & 255u), a0);
            a1 = fmaf(wsj, (float)(int)(signed char)((qv >> 8) & 255u), a1);
            a2 = fmaf(wsj, (float)(int)(signed char)((qv >> 16) & 255u), a2);
            a3 = fmaf(wsj, (float)(int)(signed char)(qv >> 24), a3);
            den += wt;
        }
    }

    float inv = 1.0f / fmaxf(den, 1e-8f);
    short4 o;
    o.x = f2bf(a0 * inv);
    o.y = f2bf(a1 * inv);
    o.z = f2bf(a2 * inv);
    o.w = f2bf(a3 * inv);
    *(short4*)(S + (size_t)node * KR + r * HID + colo) = o;
}

// ---------------------------------------------------------------------------
extern "C" void kernel_launch(void* const* d_in, const int* in_sizes, int n_in,
                              void* d_out, int out_size, void* d_ws, size_t ws_size,
                              hipStream_t stream) {
    const float* fa    = (const float*)d_in[0];
    const float* fb    = (const float*)d_in[1];
    const float* Wa    = (const float*)d_in[2];
    const float* Wb    = (const float*)d_in[3];
    const float* Wr    = (const float*)d_in[4];
    const float* gamma = (const float*)d_in[5];
    const float* beta  = (const float*)d_in[6];
    const float* ew    = (const float*)d_in[7];
    const int*   esrc  = (const int*)d_in[8];
    const int*   edst  = (const int*)d_in[9];
    float* out = (float*)d_out;

    char* ws = (char*)d_ws;
    size_t off = 0;
    short* S       = (short*)(ws + off); off += (size_t)N_NODES * KR * 2;    // 153.6 MB
    short* WTp     = (short*)(ws + off); off += (size_t)256 * KP * 2;
    short* WTr     = (short*)(ws + off); off += (size_t)256 * KR * 2;
    int*   count   = (int*)  (ws + off); off += (size_t)NKEYS * 4;
    int*   offs    = (int*)  (ws + off); off += (size_t)NKEYS * 4;
    int*   bsum    = (int*)  (ws + off); off += 4096;
    int4*  csr4    = (int4*) (ws + off); off += (size_t)N_EDGES * 16;        // 24 MB
    unsigned char* h0q = (unsigned char*)(ws + off); off += (size_t)N_NODES * HID; // 25.6 MB
    float* h0scale = (float*)(ws + off); off += (size_t)N_NODES * 4;         // 0.4 MB

    wprep_kernel<<<(256 * KP + 256 * KR) / 256, 256, 0, stream>>>(
        Wa, Wb, Wr, WTp, WTr);

    const int ngridP = (N_NODES + 255) / 256;   // 391
    proj_gemm<<<ngridP, 512, 0, stream>>>(fa, fb, WTp, h0q, h0scale);

    // CSR build (scan3 folded into fill/gather via bsum add)
    hipMemsetAsync(count, 0, (size_t)NKEYS * 4, stream);
    const int egrid = (N_EDGES + 255) / 256;
    hist_kernel<<<egrid, 256, 0, stream>>>(edst, count);
    scan1_kernel<<<NSCANBLK, 256, 0, stream>>>(count, offs, bsum);
    scan2_kernel<<<1, 256, 0, stream>>>(bsum);
    fill_kernel<<<egrid, 256, 0, stream>>>(esrc, edst, ew, h0scale, offs, bsum, csr4);

    gather_kernel<<<(N_REL * N_NODES * 64) / 256, 256, 0, stream>>>(
        h0q, offs, count, bsum, csr4, S);

    const int ngridR = (N_NODES + 127) / 128;   // 782
    rel_gemm_ln<<<ngridR, 512, 0, stream>>>(S, WTr, h0q, h0scale, gamma, beta, out);
}